// Round 1
// 334.635 us; speedup vs baseline: 1.0272x; 1.0272x over previous
//
#include <hip/hip_runtime.h>

static constexpr float NEAR_T = 0.1f;
static constexpr float FAR_T  = 3.0f;

// One ray per 64-lane wave; 2 samples per lane (s = 2*lane, 2*lane+1).
// Phase A: branchless density gather (z-pair float2 + cndmask select) -> alpha
//          -> wave product-scan -> per-sample weight.
// Phase B: SH gather only where weight > 0 (exact skip), and the z1 corner is
//          only loaded when z1 != z0 (clamped / integer z): the duplicate
//          corner reuses the z0 dot result through the SAME fmaf chain order,
//          so the result is bit-identical to loading it twice.
// 4-byte-aligned vector loads (float2/float4 at odd offsets) are legal on
// gfx950 — the previous kernel already relied on this (float4 at sp+23).
__global__ __launch_bounds__(256)
void plenoxel_render(const float* __restrict__ density,
                     const float* __restrict__ sh,
                     const float* __restrict__ origins,
                     const float* __restrict__ dirs,
                     const int*  __restrict__ ns_ptr,
                     float* __restrict__ out,
                     int nrays)
{
    const int lane = threadIdx.x & 63;
    const int ray  = (int)((blockIdx.x * blockDim.x + threadIdx.x) >> 6);
    if (ray >= nrays) return;   // wave-uniform

    const int ns = *ns_ptr;
    const float step = (FAR_T - NEAR_T) / (float)(ns - 1);

    const float ox = origins[ray*3+0];
    const float oy = origins[ray*3+1];
    const float oz = origins[ray*3+2];
    const float dx = dirs[ray*3+0];
    const float dy = dirs[ray*3+1];
    const float dz = dirs[ray*3+2];

    // Degree-2 SH basis from normalized direction (zero-guard like reference)
    float nx = dx, ny = dy, nz = dz;
    float nn = nx*nx + ny*ny + nz*nz;
    if (nn < 1e-8f) { nx = 0.0f; ny = 0.0f; nz = 1.0f; nn = 1.0f; }
    const float inv = 1.0f / sqrtf(nn);
    nx *= inv; ny *= inv; nz *= inv;

    const float B0 = 0.282095f;
    const float B1 = 0.488603f * ny;
    const float B2 = 0.488603f * nz;
    const float B3 = 0.488603f * nx;
    const float B4 = 1.092548f * nx * ny;
    const float B5 = 1.092548f * ny * nz;
    const float B6 = 0.315392f * (3.0f * nz * nz - 1.0f);
    const float B7 = 1.092548f * nx * nz;
    const float B8 = 0.546274f * (nx * nx - ny * ny);

    // ---- Phase A: geometry + density-only gather -> alpha ----
    float alpha2[2];
    float frx2[2], fry2[2], frz2[2];
    int   pk2[2];   // x0<<14 | y0<<7 | z0 | dx<<21 | dy<<22 | dz<<23

    #pragma unroll
    for (int si = 0; si < 2; ++si) {
        const int s = 2*lane + si;
        const float t = NEAR_T + (float)s * step;
        float px = ox + t*dx;
        float py = oy + t*dy;
        float pz = oz + t*dz;
        // match reference rounding: norm = 2*(p+1)*0.5 - 1 ; voxel = (n+1)*0.5*127
        px = 2.0f*(px + 1.0f)*0.5f - 1.0f;
        py = 2.0f*(py + 1.0f)*0.5f - 1.0f;
        pz = 2.0f*(pz + 1.0f)*0.5f - 1.0f;
        const float pvx = (px + 1.0f) * 0.5f * 127.0f;
        const float pvy = (py + 1.0f) * 0.5f * 127.0f;
        const float pvz = (pz + 1.0f) * 0.5f * 127.0f;

        const float fx = floorf(pvx), fy = floorf(pvy), fz = floorf(pvz);
        const float frx = pvx - fx, fry = pvy - fy, frz = pvz - fz;
        const int x0 = (int)fminf(fmaxf(fx, 0.0f), 127.0f);
        const int y0 = (int)fminf(fmaxf(fy, 0.0f), 127.0f);
        const int z0 = (int)fminf(fmaxf(fz, 0.0f), 127.0f);
        const int x1 = (int)fminf(fmaxf(ceilf(pvx), 0.0f), 127.0f);
        const int y1 = (int)fminf(fmaxf(ceilf(pvy), 0.0f), 127.0f);
        const int z1 = (int)fminf(fmaxf(ceilf(pvz), 0.0f), 127.0f);

        frx2[si] = frx; fry2[si] = fry; frz2[si] = frz;
        pk2[si] = (x0<<14) | (y0<<7) | z0
                | ((x1-x0)<<21) | ((y1-y0)<<22) | ((z1-z0)<<23);

        // Density gather: 4 (x,y) planes, z-pair as one dwordx2.
        // z1 is always z0 or z0+1 (ceil-floor in {0,1}, clamps preserve order),
        // so the pair [zb, zb+1] with zb=min(z0,126) covers every case via select.
        const int zb  = min(z0, 126);
        const int b00 = (x0<<14) + (y0<<7) + zb;
        const int b01 = (x0<<14) + (y1<<7) + zb;
        const int b10 = (x1<<14) + (y0<<7) + zb;
        const int b11 = (x1<<14) + (y1<<7) + zb;
        const float2 q00 = *(const float2*)(density + b00);
        const float2 q01 = *(const float2*)(density + b01);
        const float2 q10 = *(const float2*)(density + b10);
        const float2 q11 = *(const float2*)(density + b11);
        const bool z0lo = (z0 == zb);
        const bool z1lo = (z1 == zb);
        const float d000 = z0lo ? q00.x : q00.y;
        const float d001 = z1lo ? q00.x : q00.y;
        const float d010 = z0lo ? q01.x : q01.y;
        const float d011 = z1lo ? q01.x : q01.y;
        const float d100 = z0lo ? q10.x : q10.y;
        const float d101 = z1lo ? q10.x : q10.y;
        const float d110 = z0lo ? q11.x : q11.y;
        const float d111 = z1lo ? q11.x : q11.y;

        const float wx0 = 1.0f - frx, wy0 = 1.0f - fry, wz0 = 1.0f - frz;
        float sg;
        sg  = (wx0*wy0*wz0) * d000;
        sg += (wx0*wy0*frz) * d001;
        sg += (wx0*fry*wz0) * d010;
        sg += (wx0*fry*frz) * d011;
        sg += (frx*wy0*wz0) * d100;
        sg += (frx*wy0*frz) * d101;
        sg += (frx*fry*wz0) * d110;
        sg += (frx*fry*frz) * d111;

        const float a = 1.0f - expf(-fmaxf(sg, 0.0f) * step);
        alpha2[si] = (s < ns) ? a : 0.0f;   // branchless tail guard
    }

    // ---- wave product-scan: trans_s = prod_{j<s} (1-alpha_j+1e-10) ----
    const float a0 = (1.0f - alpha2[0]) + 1e-10f;
    const float a1 = (1.0f - alpha2[1]) + 1e-10f;

    float incl = a0 * a1;
    #pragma unroll
    for (int off = 1; off < 64; off <<= 1) {
        const float v = __shfl_up(incl, off, 64);
        incl = (lane >= off) ? incl * v : incl;
    }
    float excl = __shfl_up(incl, 1, 64);
    excl = (lane == 0) ? 1.0f : excl;

    const float wgt[2] = { alpha2[0] * excl, alpha2[1] * (excl * a0) };

    // ---- Phase B: SH gather only where weight > 0 ----
    float cr = 0.0f, cg = 0.0f, cb = 0.0f;

    #pragma unroll
    for (int si = 0; si < 2; ++si) {
        const float w = wgt[si];
        if (w > 0.0f) {
            const int pk   = pk2[si];
            const int b27  = (pk & 0x1FFFFF) * 27;
            const int dX27 = (pk & (1<<21)) ? (16384*27) : 0;
            const int dY27 = (pk & (1<<22)) ? (128*27)   : 0;
            const bool dzf = (pk & (1<<23)) != 0;

            const float frx = frx2[si], fry = fry2[si], frz = frz2[si];
            const float wxv[2] = {1.0f - frx, frx};
            const float wyv[2] = {1.0f - fry, fry};
            const float wzv[2] = {1.0f - frz, frz};

            float r0 = 0.0f, r1 = 0.0f, r2 = 0.0f;
            #pragma unroll
            for (int cx = 0; cx < 2; ++cx) {
                const int bx27 = b27 + (cx ? dX27 : 0);
                #pragma unroll
                for (int cy = 0; cy < 2; ++cy) {
                    const float cwxy = wxv[cx] * wyv[cy];
                    const float* sp = sh + (bx27 + (cy ? dY27 : 0));

                    // corner (cx,cy,z0): 7 overlapped float4 loads, dot with basis
                    float e0, e1, e2;
                    {
                        const float4 L0 = *(const float4*)(sp + 0);
                        const float4 L1 = *(const float4*)(sp + 4);
                        const float4 L2 = *(const float4*)(sp + 8);
                        const float4 L3 = *(const float4*)(sp + 12);
                        const float4 L4 = *(const float4*)(sp + 16);
                        const float4 L5 = *(const float4*)(sp + 20);
                        const float4 L6 = *(const float4*)(sp + 23);   // floats 23..26
                        e0 = L0.x*B0 + L0.y*B1 + L0.z*B2 + L0.w*B3
                           + L1.x*B4 + L1.y*B5 + L1.z*B6 + L1.w*B7
                           + L2.x*B8;
                        e1 = L2.y*B0 + L2.z*B1 + L2.w*B2
                           + L3.x*B3 + L3.y*B4 + L3.z*B5 + L3.w*B6
                           + L4.x*B7 + L4.y*B8;
                        e2 = L4.z*B0 + L4.w*B1
                           + L5.x*B2 + L5.y*B3 + L5.z*B4 + L5.w*B5
                           + L6.y*B6 + L6.z*B7 + L6.w*B8;
                    }

                    // corner (cx,cy,z1): identical to z0 when dzf==0 -> reuse
                    // the z0 dot bits instead of re-loading the same voxel.
                    float f0 = e0, f1 = e1, f2 = e2;
                    if (dzf) {
                        const float* sq = sp + 27;
                        const float4 L0 = *(const float4*)(sq + 0);
                        const float4 L1 = *(const float4*)(sq + 4);
                        const float4 L2 = *(const float4*)(sq + 8);
                        const float4 L3 = *(const float4*)(sq + 12);
                        const float4 L4 = *(const float4*)(sq + 16);
                        const float4 L5 = *(const float4*)(sq + 20);
                        const float4 L6 = *(const float4*)(sq + 23);
                        f0 = L0.x*B0 + L0.y*B1 + L0.z*B2 + L0.w*B3
                           + L1.x*B4 + L1.y*B5 + L1.z*B6 + L1.w*B7
                           + L2.x*B8;
                        f1 = L2.y*B0 + L2.z*B1 + L2.w*B2
                           + L3.x*B3 + L3.y*B4 + L3.z*B5 + L3.w*B6
                           + L4.x*B7 + L4.y*B8;
                        f2 = L4.z*B0 + L4.w*B1
                           + L5.x*B2 + L5.y*B3 + L5.z*B4 + L5.w*B5
                           + L6.y*B6 + L6.z*B7 + L6.w*B8;
                    }

                    // accumulate in the ORIGINAL corner order: (cx,cy,0) then (cx,cy,1)
                    const float cwa = cwxy * wzv[0];
                    r0 = fmaf(cwa, e0, r0);
                    r1 = fmaf(cwa, e1, r1);
                    r2 = fmaf(cwa, e2, r2);
                    const float cwb = cwxy * wzv[1];
                    r0 = fmaf(cwb, f0, r0);
                    r1 = fmaf(cwb, f1, r1);
                    r2 = fmaf(cwb, f2, r2);
                }
            }
            cr = fmaf(w, 1.0f / (1.0f + expf(-r0)), cr);
            cg = fmaf(w, 1.0f / (1.0f + expf(-r1)), cg);
            cb = fmaf(w, 1.0f / (1.0f + expf(-r2)), cb);
        }
    }

    // ---- wave reduction and write ----
    #pragma unroll
    for (int off = 32; off; off >>= 1) {
        cr += __shfl_down(cr, off, 64);
        cg += __shfl_down(cg, off, 64);
        cb += __shfl_down(cb, off, 64);
    }

    if (lane == 0) {
        out[ray*3+0] = cr;
        out[ray*3+1] = cg;
        out[ray*3+2] = cb;
    }
}

extern "C" void kernel_launch(void* const* d_in, const int* in_sizes, int n_in,
                              void* d_out, int out_size, void* d_ws, size_t ws_size,
                              hipStream_t stream) {
    const float* density = (const float*)d_in[0];
    const float* sh      = (const float*)d_in[1];
    const float* origins = (const float*)d_in[2];
    const float* dirs    = (const float*)d_in[3];
    const int*   ns_ptr  = (const int*)d_in[4];
    float* out = (float*)d_out;

    const int nrays = in_sizes[2] / 3;
    const int threads = 256;                       // 4 rays per block
    const int blocks = (nrays * 64 + threads - 1) / threads;
    plenoxel_render<<<blocks, threads, 0, stream>>>(density, sh, origins, dirs,
                                                    ns_ptr, out, nrays);
}

// Round 2
// 316.881 us; speedup vs baseline: 1.0848x; 1.0560x over previous
//
#include <hip/hip_runtime.h>

static constexpr float NEAR_T = 0.1f;
static constexpr float FAR_T  = 3.0f;

// One ray per 64-lane wave; 2 samples per lane (s = 2*lane, 2*lane+1).
// Phase A: density gather with full x/y/z duplicate-corner elimination
//          (clamped axes collapse floor==ceil -> identical addresses) -> alpha
//          -> wave product-scan -> per-sample weight.
// Phase B: SH gather only where weight > 0 (exact skip). Each of the 8 corner
//          dot-products is computed from a LOAD only when its address differs
//          from an already-computed corner; otherwise the stored dot result is
//          reused. Identical address => identical bits => identical dot, and
//          the fmaf accumulation chain keeps the original (cx,cy,cz) order,
//          so the result is bit-identical to the naive 8-corner version.
__global__ __launch_bounds__(256)
void plenoxel_render(const float* __restrict__ density,
                     const float* __restrict__ sh,
                     const float* __restrict__ origins,
                     const float* __restrict__ dirs,
                     const int*  __restrict__ ns_ptr,
                     float* __restrict__ out,
                     int nrays)
{
    const int lane = threadIdx.x & 63;
    const int ray  = (int)((blockIdx.x * blockDim.x + threadIdx.x) >> 6);
    if (ray >= nrays) return;   // wave-uniform

    const int ns = *ns_ptr;
    const float step = (FAR_T - NEAR_T) / (float)(ns - 1);

    const float ox = origins[ray*3+0];
    const float oy = origins[ray*3+1];
    const float oz = origins[ray*3+2];
    const float dx = dirs[ray*3+0];
    const float dy = dirs[ray*3+1];
    const float dz = dirs[ray*3+2];

    // Degree-2 SH basis from normalized direction (zero-guard like reference)
    float nx = dx, ny = dy, nz = dz;
    float nn = nx*nx + ny*ny + nz*nz;
    if (nn < 1e-8f) { nx = 0.0f; ny = 0.0f; nz = 1.0f; nn = 1.0f; }
    const float inv = 1.0f / sqrtf(nn);
    nx *= inv; ny *= inv; nz *= inv;

    const float B0 = 0.282095f;
    const float B1 = 0.488603f * ny;
    const float B2 = 0.488603f * nz;
    const float B3 = 0.488603f * nx;
    const float B4 = 1.092548f * nx * ny;
    const float B5 = 1.092548f * ny * nz;
    const float B6 = 0.315392f * (3.0f * nz * nz - 1.0f);
    const float B7 = 1.092548f * nx * nz;
    const float B8 = 0.546274f * (nx * nx - ny * ny);

    // ---- Phase A: geometry + density-only gather -> alpha ----
    float alpha2[2];
    float frx2[2], fry2[2], frz2[2];
    int   pk2[2];   // x0<<14 | y0<<7 | z0 | dxf<<21 | dyf<<22 | dzf<<23

    #pragma unroll
    for (int si = 0; si < 2; ++si) {
        const int s = 2*lane + si;
        const float t = NEAR_T + (float)s * step;
        float px = ox + t*dx;
        float py = oy + t*dy;
        float pz = oz + t*dz;
        // match reference rounding: norm = 2*(p+1)*0.5 - 1 ; voxel = (n+1)*0.5*127
        px = 2.0f*(px + 1.0f)*0.5f - 1.0f;
        py = 2.0f*(py + 1.0f)*0.5f - 1.0f;
        pz = 2.0f*(pz + 1.0f)*0.5f - 1.0f;
        const float pvx = (px + 1.0f) * 0.5f * 127.0f;
        const float pvy = (py + 1.0f) * 0.5f * 127.0f;
        const float pvz = (pz + 1.0f) * 0.5f * 127.0f;

        const float fx = floorf(pvx), fy = floorf(pvy), fz = floorf(pvz);
        const float frx = pvx - fx, fry = pvy - fy, frz = pvz - fz;
        const int x0 = (int)fminf(fmaxf(fx, 0.0f), 127.0f);
        const int y0 = (int)fminf(fmaxf(fy, 0.0f), 127.0f);
        const int z0 = (int)fminf(fmaxf(fz, 0.0f), 127.0f);
        const int x1 = (int)fminf(fmaxf(ceilf(pvx), 0.0f), 127.0f);
        const int y1 = (int)fminf(fmaxf(ceilf(pvy), 0.0f), 127.0f);
        const int z1 = (int)fminf(fmaxf(ceilf(pvz), 0.0f), 127.0f);

        const bool dxf = (x1 != x0);
        const bool dyf = (y1 != y0);
        const bool dzf = (z1 != z0);

        frx2[si] = frx; fry2[si] = fry; frz2[si] = frz;
        pk2[si] = (x0<<14) | (y0<<7) | z0
                | (dxf ? (1<<21) : 0) | (dyf ? (1<<22) : 0) | (dzf ? (1<<23) : 0);

        // Density gather: up to 4 (x,y) planes, z-pair as one dwordx2.
        // z1 is always z0 or z0+1, so the pair [zb, zb+1] with zb=min(z0,126)
        // covers every case via select. Duplicate x/y planes (clamped axes)
        // reuse the already-loaded pair -> exec-masked lanes issue no loads.
        const int zb  = min(z0, 126);
        const int b00 = (x0<<14) + (y0<<7) + zb;
        const float2 q00 = *(const float2*)(density + b00);
        float2 q01, q10, q11;
        if (dyf) q01 = *(const float2*)(density + ((x0<<14) + (y1<<7) + zb));
        else     q01 = q00;
        if (dxf) {
            q10 = *(const float2*)(density + ((x1<<14) + (y0<<7) + zb));
            if (dyf) q11 = *(const float2*)(density + ((x1<<14) + (y1<<7) + zb));
            else     q11 = q10;
        } else {
            q10 = q00;
            q11 = q01;
        }
        const bool z0lo = (z0 == zb);
        const bool z1lo = (z1 == zb);
        const float d000 = z0lo ? q00.x : q00.y;
        const float d001 = z1lo ? q00.x : q00.y;
        const float d010 = z0lo ? q01.x : q01.y;
        const float d011 = z1lo ? q01.x : q01.y;
        const float d100 = z0lo ? q10.x : q10.y;
        const float d101 = z1lo ? q10.x : q10.y;
        const float d110 = z0lo ? q11.x : q11.y;
        const float d111 = z1lo ? q11.x : q11.y;

        const float wx0 = 1.0f - frx, wy0 = 1.0f - fry, wz0 = 1.0f - frz;
        float sg;
        sg  = (wx0*wy0*wz0) * d000;
        sg += (wx0*wy0*frz) * d001;
        sg += (wx0*fry*wz0) * d010;
        sg += (wx0*fry*frz) * d011;
        sg += (frx*wy0*wz0) * d100;
        sg += (frx*wy0*frz) * d101;
        sg += (frx*fry*wz0) * d110;
        sg += (frx*fry*frz) * d111;

        const float a = 1.0f - expf(-fmaxf(sg, 0.0f) * step);
        alpha2[si] = (s < ns) ? a : 0.0f;   // branchless tail guard
    }

    // ---- wave product-scan: trans_s = prod_{j<s} (1-alpha_j+1e-10) ----
    const float a0 = (1.0f - alpha2[0]) + 1e-10f;
    const float a1 = (1.0f - alpha2[1]) + 1e-10f;

    float incl = a0 * a1;
    #pragma unroll
    for (int off = 1; off < 64; off <<= 1) {
        const float v = __shfl_up(incl, off, 64);
        incl = (lane >= off) ? incl * v : incl;
    }
    float excl = __shfl_up(incl, 1, 64);
    excl = (lane == 0) ? 1.0f : excl;

    const float wgt[2] = { alpha2[0] * excl, alpha2[1] * (excl * a0) };

    // ---- Phase B: SH gather only where weight > 0 ----
    float cr = 0.0f, cg = 0.0f, cb = 0.0f;

    // 27-float SH voxel -> 3-channel dot with the basis (7 overlapped float4s)
    auto dot27 = [&](const float* sp, float* o) {
        const float4 L0 = *(const float4*)(sp + 0);
        const float4 L1 = *(const float4*)(sp + 4);
        const float4 L2 = *(const float4*)(sp + 8);
        const float4 L3 = *(const float4*)(sp + 12);
        const float4 L4 = *(const float4*)(sp + 16);
        const float4 L5 = *(const float4*)(sp + 20);
        const float4 L6 = *(const float4*)(sp + 23);   // floats 23..26
        o[0] = L0.x*B0 + L0.y*B1 + L0.z*B2 + L0.w*B3
             + L1.x*B4 + L1.y*B5 + L1.z*B6 + L1.w*B7
             + L2.x*B8;
        o[1] = L2.y*B0 + L2.z*B1 + L2.w*B2
             + L3.x*B3 + L3.y*B4 + L3.z*B5 + L3.w*B6
             + L4.x*B7 + L4.y*B8;
        o[2] = L4.z*B0 + L4.w*B1
             + L5.x*B2 + L5.y*B3 + L5.z*B4 + L5.w*B5
             + L6.y*B6 + L6.z*B7 + L6.w*B8;
    };

    #pragma unroll
    for (int si = 0; si < 2; ++si) {
        const float w = wgt[si];
        if (w > 0.0f) {
            const int  pk  = pk2[si];
            const int  b27 = (pk & 0x1FFFFF) * 27;
            const bool dxf = (pk & (1<<21)) != 0;
            const bool dyf = (pk & (1<<22)) != 0;
            const bool dzf = (pk & (1<<23)) != 0;
            const float* base = sh + b27;

            // Corner dots: e = z0 plane, f = z1 plane, for xy planes 00,01,10,11.
            // Load only unique addresses; reuse stored dots for duplicates.
            float e00[3], f00[3], e01[3], f01[3], e10[3], f10[3], e11[3], f11[3];

            dot27(base, e00);
            if (dzf) dot27(base + 27, f00);
            else { f00[0]=e00[0]; f00[1]=e00[1]; f00[2]=e00[2]; }

            if (dyf) {
                const float* p01 = base + 128*27;
                dot27(p01, e01);
                if (dzf) dot27(p01 + 27, f01);
                else { f01[0]=e01[0]; f01[1]=e01[1]; f01[2]=e01[2]; }
            } else {
                e01[0]=e00[0]; e01[1]=e00[1]; e01[2]=e00[2];
                f01[0]=f00[0]; f01[1]=f00[1]; f01[2]=f00[2];
            }

            if (dxf) {
                const float* p10 = base + 16384*27;
                dot27(p10, e10);
                if (dzf) dot27(p10 + 27, f10);
                else { f10[0]=e10[0]; f10[1]=e10[1]; f10[2]=e10[2]; }
                if (dyf) {
                    const float* p11 = p10 + 128*27;
                    dot27(p11, e11);
                    if (dzf) dot27(p11 + 27, f11);
                    else { f11[0]=e11[0]; f11[1]=e11[1]; f11[2]=e11[2]; }
                } else {
                    e11[0]=e10[0]; e11[1]=e10[1]; e11[2]=e10[2];
                    f11[0]=f10[0]; f11[1]=f10[1]; f11[2]=f10[2];
                }
            } else {
                e10[0]=e00[0]; e10[1]=e00[1]; e10[2]=e00[2];
                f10[0]=f00[0]; f10[1]=f00[1]; f10[2]=f00[2];
                e11[0]=e01[0]; e11[1]=e01[1]; e11[2]=e01[2];
                f11[0]=f01[0]; f11[1]=f01[1]; f11[2]=f01[2];
            }

            // Accumulate in the ORIGINAL corner order:
            // (0,0,z0),(0,0,z1),(0,1,z0),(0,1,z1),(1,0,z0),(1,0,z1),(1,1,z0),(1,1,z1)
            const float frx = frx2[si], fry = fry2[si], frz = frz2[si];
            const float wx0 = 1.0f - frx, wy0 = 1.0f - fry, wz0 = 1.0f - frz;

            float r0 = 0.0f, r1 = 0.0f, r2 = 0.0f;
            {
                const float cwxy = wx0 * wy0;
                const float cwa = cwxy * wz0, cwb = cwxy * frz;
                r0 = fmaf(cwa, e00[0], r0); r1 = fmaf(cwa, e00[1], r1); r2 = fmaf(cwa, e00[2], r2);
                r0 = fmaf(cwb, f00[0], r0); r1 = fmaf(cwb, f00[1], r1); r2 = fmaf(cwb, f00[2], r2);
            }
            {
                const float cwxy = wx0 * fry;
                const float cwa = cwxy * wz0, cwb = cwxy * frz;
                r0 = fmaf(cwa, e01[0], r0); r1 = fmaf(cwa, e01[1], r1); r2 = fmaf(cwa, e01[2], r2);
                r0 = fmaf(cwb, f01[0], r0); r1 = fmaf(cwb, f01[1], r1); r2 = fmaf(cwb, f01[2], r2);
            }
            {
                const float cwxy = frx * wy0;
                const float cwa = cwxy * wz0, cwb = cwxy * frz;
                r0 = fmaf(cwa, e10[0], r0); r1 = fmaf(cwa, e10[1], r1); r2 = fmaf(cwa, e10[2], r2);
                r0 = fmaf(cwb, f10[0], r0); r1 = fmaf(cwb, f10[1], r1); r2 = fmaf(cwb, f10[2], r2);
            }
            {
                const float cwxy = frx * fry;
                const float cwa = cwxy * wz0, cwb = cwxy * frz;
                r0 = fmaf(cwa, e11[0], r0); r1 = fmaf(cwa, e11[1], r1); r2 = fmaf(cwa, e11[2], r2);
                r0 = fmaf(cwb, f11[0], r0); r1 = fmaf(cwb, f11[1], r1); r2 = fmaf(cwb, f11[2], r2);
            }

            cr = fmaf(w, 1.0f / (1.0f + expf(-r0)), cr);
            cg = fmaf(w, 1.0f / (1.0f + expf(-r1)), cg);
            cb = fmaf(w, 1.0f / (1.0f + expf(-r2)), cb);
        }
    }

    // ---- wave reduction and write ----
    #pragma unroll
    for (int off = 32; off; off >>= 1) {
        cr += __shfl_down(cr, off, 64);
        cg += __shfl_down(cg, off, 64);
        cb += __shfl_down(cb, off, 64);
    }

    if (lane == 0) {
        out[ray*3+0] = cr;
        out[ray*3+1] = cg;
        out[ray*3+2] = cb;
    }
}

extern "C" void kernel_launch(void* const* d_in, const int* in_sizes, int n_in,
                              void* d_out, int out_size, void* d_ws, size_t ws_size,
                              hipStream_t stream) {
    const float* density = (const float*)d_in[0];
    const float* sh      = (const float*)d_in[1];
    const float* origins = (const float*)d_in[2];
    const float* dirs    = (const float*)d_in[3];
    const int*   ns_ptr  = (const int*)d_in[4];
    float* out = (float*)d_out;

    const int nrays = in_sizes[2] / 3;
    const int threads = 256;                       // 4 rays per block
    const int blocks = (nrays * 64 + threads - 1) / threads;
    plenoxel_render<<<blocks, threads, 0, stream>>>(density, sh, origins, dirs,
                                                    ns_ptr, out, nrays);
}

// Round 3
// 316.145 us; speedup vs baseline: 1.0873x; 1.0023x over previous
//
#include <hip/hip_runtime.h>

static constexpr float NEAR_T = 0.1f;
static constexpr float FAR_T  = 3.0f;

// One ray per 64-lane wave; 2 samples per lane (s = 2*lane, 2*lane+1).
// Phase A: density gather with x/y/z duplicate-corner elimination -> alpha
//          -> wave product-scan -> per-sample weight.
// Phase B: SH gather only where weight > 0 (exact skip), unique-corner loads
//          only, with IMMEDIATE in-order accumulation (corner order
//          (0,0,z0),(0,0,z1),(0,1,z0),(0,1,z1),(1,0,..),(1,1,..)) so the last
//          corners never occupy registers. Identical addresses => identical
//          bits => identical dots; the fmaf chain order and weight products
//          are byte-identical to the naive 8-corner version.
// __launch_bounds__(256,4): force VGPR<=128 so 4 blocks/CU (4 waves/SIMD)
// are resident -- the scattered L3-latency gather needs the extra wave to
// cover stalls (occupancy-tier theory, round 3).
__global__ __launch_bounds__(256, 4)
void plenoxel_render(const float* __restrict__ density,
                     const float* __restrict__ sh,
                     const float* __restrict__ origins,
                     const float* __restrict__ dirs,
                     const int*  __restrict__ ns_ptr,
                     float* __restrict__ out,
                     int nrays)
{
    const int lane = threadIdx.x & 63;
    const int ray  = (int)((blockIdx.x * blockDim.x + threadIdx.x) >> 6);
    if (ray >= nrays) return;   // wave-uniform

    const int ns = *ns_ptr;
    const float step = (FAR_T - NEAR_T) / (float)(ns - 1);

    const float ox = origins[ray*3+0];
    const float oy = origins[ray*3+1];
    const float oz = origins[ray*3+2];
    const float dx = dirs[ray*3+0];
    const float dy = dirs[ray*3+1];
    const float dz = dirs[ray*3+2];

    // Degree-2 SH basis from normalized direction (zero-guard like reference)
    float nx = dx, ny = dy, nz = dz;
    float nn = nx*nx + ny*ny + nz*nz;
    if (nn < 1e-8f) { nx = 0.0f; ny = 0.0f; nz = 1.0f; nn = 1.0f; }
    const float inv = 1.0f / sqrtf(nn);
    nx *= inv; ny *= inv; nz *= inv;

    const float B0 = 0.282095f;
    const float B1 = 0.488603f * ny;
    const float B2 = 0.488603f * nz;
    const float B3 = 0.488603f * nx;
    const float B4 = 1.092548f * nx * ny;
    const float B5 = 1.092548f * ny * nz;
    const float B6 = 0.315392f * (3.0f * nz * nz - 1.0f);
    const float B7 = 1.092548f * nx * nz;
    const float B8 = 0.546274f * (nx * nx - ny * ny);

    // ---- Phase A: geometry + density-only gather -> alpha ----
    float alpha2[2];
    float frx2[2], fry2[2], frz2[2];
    int   pk2[2];   // x0<<14 | y0<<7 | z0 | dxf<<21 | dyf<<22 | dzf<<23

    #pragma unroll
    for (int si = 0; si < 2; ++si) {
        const int s = 2*lane + si;
        const float t = NEAR_T + (float)s * step;
        float px = ox + t*dx;
        float py = oy + t*dy;
        float pz = oz + t*dz;
        // match reference rounding: norm = 2*(p+1)*0.5 - 1 ; voxel = (n+1)*0.5*127
        px = 2.0f*(px + 1.0f)*0.5f - 1.0f;
        py = 2.0f*(py + 1.0f)*0.5f - 1.0f;
        pz = 2.0f*(pz + 1.0f)*0.5f - 1.0f;
        const float pvx = (px + 1.0f) * 0.5f * 127.0f;
        const float pvy = (py + 1.0f) * 0.5f * 127.0f;
        const float pvz = (pz + 1.0f) * 0.5f * 127.0f;

        const float fx = floorf(pvx), fy = floorf(pvy), fz = floorf(pvz);
        const float frx = pvx - fx, fry = pvy - fy, frz = pvz - fz;
        const int x0 = (int)fminf(fmaxf(fx, 0.0f), 127.0f);
        const int y0 = (int)fminf(fmaxf(fy, 0.0f), 127.0f);
        const int z0 = (int)fminf(fmaxf(fz, 0.0f), 127.0f);
        const int x1 = (int)fminf(fmaxf(ceilf(pvx), 0.0f), 127.0f);
        const int y1 = (int)fminf(fmaxf(ceilf(pvy), 0.0f), 127.0f);
        const int z1 = (int)fminf(fmaxf(ceilf(pvz), 0.0f), 127.0f);

        const bool dxf = (x1 != x0);
        const bool dyf = (y1 != y0);
        const bool dzf = (z1 != z0);

        frx2[si] = frx; fry2[si] = fry; frz2[si] = frz;
        pk2[si] = (x0<<14) | (y0<<7) | z0
                | (dxf ? (1<<21) : 0) | (dyf ? (1<<22) : 0) | (dzf ? (1<<23) : 0);

        // Density gather: up to 4 (x,y) planes, z-pair as one dwordx2.
        // z1 is always z0 or z0+1, so the pair [zb, zb+1] with zb=min(z0,126)
        // covers every case via select. Duplicate x/y planes (clamped axes)
        // reuse the already-loaded pair -> exec-masked lanes issue no loads.
        const int zb  = min(z0, 126);
        const int b00 = (x0<<14) + (y0<<7) + zb;
        const float2 q00 = *(const float2*)(density + b00);
        float2 q01, q10, q11;
        if (dyf) q01 = *(const float2*)(density + ((x0<<14) + (y1<<7) + zb));
        else     q01 = q00;
        if (dxf) {
            q10 = *(const float2*)(density + ((x1<<14) + (y0<<7) + zb));
            if (dyf) q11 = *(const float2*)(density + ((x1<<14) + (y1<<7) + zb));
            else     q11 = q10;
        } else {
            q10 = q00;
            q11 = q01;
        }
        const bool z0lo = (z0 == zb);
        const bool z1lo = (z1 == zb);
        const float d000 = z0lo ? q00.x : q00.y;
        const float d001 = z1lo ? q00.x : q00.y;
        const float d010 = z0lo ? q01.x : q01.y;
        const float d011 = z1lo ? q01.x : q01.y;
        const float d100 = z0lo ? q10.x : q10.y;
        const float d101 = z1lo ? q10.x : q10.y;
        const float d110 = z0lo ? q11.x : q11.y;
        const float d111 = z1lo ? q11.x : q11.y;

        const float wx0 = 1.0f - frx, wy0 = 1.0f - fry, wz0 = 1.0f - frz;
        float sg;
        sg  = (wx0*wy0*wz0) * d000;
        sg += (wx0*wy0*frz) * d001;
        sg += (wx0*fry*wz0) * d010;
        sg += (wx0*fry*frz) * d011;
        sg += (frx*wy0*wz0) * d100;
        sg += (frx*wy0*frz) * d101;
        sg += (frx*fry*wz0) * d110;
        sg += (frx*fry*frz) * d111;

        const float a = 1.0f - expf(-fmaxf(sg, 0.0f) * step);
        alpha2[si] = (s < ns) ? a : 0.0f;   // branchless tail guard
    }

    // ---- wave product-scan: trans_s = prod_{j<s} (1-alpha_j+1e-10) ----
    const float a0 = (1.0f - alpha2[0]) + 1e-10f;
    const float a1 = (1.0f - alpha2[1]) + 1e-10f;

    float incl = a0 * a1;
    #pragma unroll
    for (int off = 1; off < 64; off <<= 1) {
        const float v = __shfl_up(incl, off, 64);
        incl = (lane >= off) ? incl * v : incl;
    }
    float excl = __shfl_up(incl, 1, 64);
    excl = (lane == 0) ? 1.0f : excl;

    const float wgt[2] = { alpha2[0] * excl, alpha2[1] * (excl * a0) };

    // ---- Phase B: SH gather only where weight > 0 ----
    float cr = 0.0f, cg = 0.0f, cb = 0.0f;

    // 27-float SH voxel -> 3-channel dot with the basis (7 overlapped float4s)
    auto dot27 = [&](const float* sp, float* o) {
        const float4 L0 = *(const float4*)(sp + 0);
        const float4 L1 = *(const float4*)(sp + 4);
        const float4 L2 = *(const float4*)(sp + 8);
        const float4 L3 = *(const float4*)(sp + 12);
        const float4 L4 = *(const float4*)(sp + 16);
        const float4 L5 = *(const float4*)(sp + 20);
        const float4 L6 = *(const float4*)(sp + 23);   // floats 23..26
        o[0] = L0.x*B0 + L0.y*B1 + L0.z*B2 + L0.w*B3
             + L1.x*B4 + L1.y*B5 + L1.z*B6 + L1.w*B7
             + L2.x*B8;
        o[1] = L2.y*B0 + L2.z*B1 + L2.w*B2
             + L3.x*B3 + L3.y*B4 + L3.z*B5 + L3.w*B6
             + L4.x*B7 + L4.y*B8;
        o[2] = L4.z*B0 + L4.w*B1
             + L5.x*B2 + L5.y*B3 + L5.z*B4 + L5.w*B5
             + L6.y*B6 + L6.z*B7 + L6.w*B8;
    };

    #pragma unroll
    for (int si = 0; si < 2; ++si) {
        const float w = wgt[si];
        if (w > 0.0f) {
            const int  pk  = pk2[si];
            const int  b27 = (pk & 0x1FFFFF) * 27;
            const bool dxf = (pk & (1<<21)) != 0;
            const bool dyf = (pk & (1<<22)) != 0;
            const bool dzf = (pk & (1<<23)) != 0;
            const float* base = sh + b27;

            const float frx = frx2[si], fry = fry2[si], frz = frz2[si];
            const float wx0 = 1.0f - frx, wy0 = 1.0f - fry, wz0 = 1.0f - frz;

            float r0 = 0.0f, r1 = 0.0f, r2 = 0.0f;

            // (0,0) plane -------------------------------------------------
            float e00[3], f00[3];
            dot27(base, e00);
            {
                const float cwxy = wx0 * wy0;
                const float cwa = cwxy * wz0;
                r0 = fmaf(cwa, e00[0], r0); r1 = fmaf(cwa, e00[1], r1); r2 = fmaf(cwa, e00[2], r2);
                if (dzf) dot27(base + 27, f00);
                else { f00[0]=e00[0]; f00[1]=e00[1]; f00[2]=e00[2]; }
                const float cwb = cwxy * frz;
                r0 = fmaf(cwb, f00[0], r0); r1 = fmaf(cwb, f00[1], r1); r2 = fmaf(cwb, f00[2], r2);
            }

            // (0,1) plane -------------------------------------------------
            float e01[3], f01[3];
            {
                if (dyf) dot27(base + 128*27, e01);
                else { e01[0]=e00[0]; e01[1]=e00[1]; e01[2]=e00[2]; }
                const float cwxy = wx0 * fry;
                const float cwa = cwxy * wz0;
                r0 = fmaf(cwa, e01[0], r0); r1 = fmaf(cwa, e01[1], r1); r2 = fmaf(cwa, e01[2], r2);
                if (dyf) {
                    if (dzf) dot27(base + 128*27 + 27, f01);
                    else { f01[0]=e01[0]; f01[1]=e01[1]; f01[2]=e01[2]; }
                } else { f01[0]=f00[0]; f01[1]=f00[1]; f01[2]=f00[2]; }
                const float cwb = cwxy * frz;
                r0 = fmaf(cwb, f01[0], r0); r1 = fmaf(cwb, f01[1], r1); r2 = fmaf(cwb, f01[2], r2);
            }

            // (1,0) plane -------------------------------------------------
            float e10[3], f10[3];
            {
                const float* p10 = base + 16384*27;
                if (dxf) dot27(p10, e10);
                else { e10[0]=e00[0]; e10[1]=e00[1]; e10[2]=e00[2]; }
                const float cwxy = frx * wy0;
                const float cwa = cwxy * wz0;
                r0 = fmaf(cwa, e10[0], r0); r1 = fmaf(cwa, e10[1], r1); r2 = fmaf(cwa, e10[2], r2);
                if (dxf) {
                    if (dzf) dot27(p10 + 27, f10);
                    else { f10[0]=e10[0]; f10[1]=e10[1]; f10[2]=e10[2]; }
                } else { f10[0]=f00[0]; f10[1]=f00[1]; f10[2]=f00[2]; }
                const float cwb = cwxy * frz;
                r0 = fmaf(cwb, f10[0], r0); r1 = fmaf(cwb, f10[1], r1); r2 = fmaf(cwb, f10[2], r2);
            }

            // (1,1) plane — never stored past its own accumulation --------
            {
                const float* p11 = base + 16384*27 + 128*27;
                float e11[3], f11[3];
                if (dxf) {
                    if (dyf) dot27(p11, e11);
                    else { e11[0]=e10[0]; e11[1]=e10[1]; e11[2]=e10[2]; }
                } else { e11[0]=e01[0]; e11[1]=e01[1]; e11[2]=e01[2]; }
                const float cwxy = frx * fry;
                const float cwa = cwxy * wz0;
                r0 = fmaf(cwa, e11[0], r0); r1 = fmaf(cwa, e11[1], r1); r2 = fmaf(cwa, e11[2], r2);
                if (dxf) {
                    if (dyf) {
                        if (dzf) dot27(p11 + 27, f11);
                        else { f11[0]=e11[0]; f11[1]=e11[1]; f11[2]=e11[2]; }
                    } else { f11[0]=f10[0]; f11[1]=f10[1]; f11[2]=f10[2]; }
                } else { f11[0]=f01[0]; f11[1]=f01[1]; f11[2]=f01[2]; }
                const float cwb = cwxy * frz;
                r0 = fmaf(cwb, f11[0], r0); r1 = fmaf(cwb, f11[1], r1); r2 = fmaf(cwb, f11[2], r2);
            }

            cr = fmaf(w, 1.0f / (1.0f + expf(-r0)), cr);
            cg = fmaf(w, 1.0f / (1.0f + expf(-r1)), cg);
            cb = fmaf(w, 1.0f / (1.0f + expf(-r2)), cb);
        }
    }

    // ---- wave reduction and write ----
    #pragma unroll
    for (int off = 32; off; off >>= 1) {
        cr += __shfl_down(cr, off, 64);
        cg += __shfl_down(cg, off, 64);
        cb += __shfl_down(cb, off, 64);
    }

    if (lane == 0) {
        out[ray*3+0] = cr;
        out[ray*3+1] = cg;
        out[ray*3+2] = cb;
    }
}

extern "C" void kernel_launch(void* const* d_in, const int* in_sizes, int n_in,
                              void* d_out, int out_size, void* d_ws, size_t ws_size,
                              hipStream_t stream) {
    const float* density = (const float*)d_in[0];
    const float* sh      = (const float*)d_in[1];
    const float* origins = (const float*)d_in[2];
    const float* dirs    = (const float*)d_in[3];
    const int*   ns_ptr  = (const int*)d_in[4];
    float* out = (float*)d_out;

    const int nrays = in_sizes[2] / 3;
    const int threads = 256;                       // 4 rays per block
    const int blocks = (nrays * 64 + threads - 1) / threads;
    plenoxel_render<<<blocks, threads, 0, stream>>>(density, sh, origins, dirs,
                                                    ns_ptr, out, nrays);
}